// Round 3
// baseline (748.252 us; speedup 1.0000x reference)
//
#include <hip/hip_runtime.h>

#define DIM 4096
#define NH 32
#define NKV 8
#define HD 128
#define WINDOW 1024
#define SEQ 2048

typedef unsigned int uint32;
typedef __attribute__((ext_vector_type(8))) short short8_t;
typedef __attribute__((ext_vector_type(8))) __bf16 bf16x8_t;
typedef __attribute__((ext_vector_type(4))) float floatx4_t;

__device__ __forceinline__ uint32 f2bf_bits(float f) {
  uint32 u = __builtin_bit_cast(uint32, f);
  return (u + 0x7fffu + ((u >> 16) & 1u)) >> 16;
}
__device__ __forceinline__ float bf2f(unsigned short b) {
  return __builtin_bit_cast(float, ((uint32)b) << 16);
}

template <class X, class Y> struct same_t { static constexpr bool v = false; };
template <class X> struct same_t<X, X> { static constexpr bool v = true; };

__device__ __forceinline__ void load_lds16(const unsigned short* g, unsigned short* l) {
  __builtin_amdgcn_global_load_lds((__attribute__((address_space(1))) void*)g,
                                   (__attribute__((address_space(3))) void*)l, 16, 0, 0);
}

// ============================================================================
// bf16 GEMM (m97-style): C[M,N] = A[M,K]*B[N,K]^T, global_load_lds width-16
// staging, XOR col8 swizzle, 128x128 tile, BK=64, 4 waves x (4x4) MFMA.
// ============================================================================
template <typename TC>
__global__ __launch_bounds__(256) void gemm_bf16(const unsigned short* __restrict__ A,
                                                 const unsigned short* __restrict__ B,
                                                 TC* __restrict__ C,
                                                 int M, int N, int K) {
  __shared__ unsigned short As[128 * 64];
  __shared__ unsigned short Bs[128 * 64];
  const int tid = threadIdx.x;
  const int lane = tid & 63, w = tid >> 6;
  const int quad = lane >> 4, l16 = lane & 15;
  const int wm = w >> 1, wn = w & 1;
  const size_t m0 = (size_t)blockIdx.y * 128, n0 = (size_t)blockIdx.x * 128;

  const int srow = tid >> 3;
  const int scol = ((tid & 7) ^ (srow & 7)) << 3;
  const unsigned short* Abase = A + (m0 + srow) * (size_t)K + scol;
  const unsigned short* Bbase = B + (n0 + srow) * (size_t)K + scol;
  unsigned short* ldsA = As + (tid >> 6) * 512;
  unsigned short* ldsB = Bs + (tid >> 6) * 512;

  const int sa = l16 & 7;
  const int raA = wm * 64 + l16;
  const int raB = wn * 64 + l16;

  floatx4_t acc[4][4] = {};

  const int nk = K >> 6;
  for (int kt = 0; kt < nk; kt++) {
    const int kbase = kt << 6;
#pragma unroll
    for (int i = 0; i < 4; i++) {
      load_lds16(Abase + kbase + (size_t)(i * 32) * K, ldsA + i * 2048);
      load_lds16(Bbase + kbase + (size_t)(i * 32) * K, ldsB + i * 2048);
    }
    __syncthreads();
#pragma unroll
    for (int ks = 0; ks < 2; ks++) {
      bf16x8_t af[4], bfg[4];
#pragma unroll
      for (int i = 0; i < 4; i++) {
        const int colA = (((ks << 2) | quad) ^ sa) << 3;
        af[i] = __builtin_bit_cast(bf16x8_t,
            *(const short8_t*)(&As[(raA + i * 16) * 64 + colA]));
      }
#pragma unroll
      for (int j = 0; j < 4; j++) {
        const int colB = (((ks << 2) | quad) ^ sa) << 3;
        bfg[j] = __builtin_bit_cast(bf16x8_t,
            *(const short8_t*)(&Bs[(raB + j * 16) * 64 + colB]));
      }
#pragma unroll
      for (int i = 0; i < 4; i++)
#pragma unroll
        for (int j = 0; j < 4; j++)
          acc[i][j] = __builtin_amdgcn_mfma_f32_16x16x32_bf16(af[i], bfg[j], acc[i][j], 0, 0, 0);
    }
    __syncthreads();
  }
#pragma unroll
  for (int i = 0; i < 4; i++)
#pragma unroll
    for (int j = 0; j < 4; j++)
#pragma unroll
      for (int r = 0; r < 4; r++) {
        size_t row = m0 + wm * 64 + i * 16 + quad * 4 + r;
        size_t col = n0 + wn * 64 + j * 16 + l16;
        float v = acc[i][j][r];
        if constexpr (same_t<TC, float>::v)
          C[row * (size_t)N + col] = v;
        else
          C[row * (size_t)N + col] = (unsigned short)f2bf_bits(v);
      }
}

// fp32 -> bf16 convert, 8 elems/thread
__global__ __launch_bounds__(256) void cvt_kernel(const float* __restrict__ in,
                                                  unsigned short* __restrict__ out, int n8) {
  int idx = blockIdx.x * 256 + threadIdx.x;
  if (idx >= n8) return;
  const float4* p = (const float4*)in + (size_t)idx * 2;
  float4 a = p[0], b = p[1];
  uint32 w0 = f2bf_bits(a.x) | (f2bf_bits(a.y) << 16);
  uint32 w1 = f2bf_bits(a.z) | (f2bf_bits(a.w) << 16);
  uint32 w2 = f2bf_bits(b.x) | (f2bf_bits(b.y) << 16);
  uint32 w3 = f2bf_bits(b.z) | (f2bf_bits(b.w) << 16);
  ((uint4*)out)[idx] = make_uint4(w0, w1, w2, w3);
}

// In-place RoPE on bf16 tensor, leading dim ld, H heads of 128.
__global__ __launch_bounds__(256) void rope_kernel(unsigned short* __restrict__ t,
                                                   const float* __restrict__ cosp,
                                                   const float* __restrict__ sinp,
                                                   int H, int ld) {
  const int idx = blockIdx.x * 256 + threadIdx.x;
  const int j = idx & 63;
  const int rem = idx >> 6;
  const int hh = rem % H;
  const int s = rem / H;
  const size_t base = (size_t)s * ld + hh * 128 + (j << 1);
  const float t0 = bf2f(t[base]), t1 = bf2f(t[base + 1]);
  const float c = cosp[s * 64 + j], sn = sinp[s * 64 + j];
  t[base] = (unsigned short)f2bf_bits(t0 * c - t1 * sn);
  t[base + 1] = (unsigned short)f2bf_bits(t0 * sn + t1 * c);
}

// v [s][r] (ld 2048) -> vT [r][s], 64x64 LDS tiles
__global__ __launch_bounds__(256) void vtrans_kernel(const unsigned short* __restrict__ v,
                                                     unsigned short* __restrict__ vT) {
  __shared__ unsigned short t[64][72];
  const int s0 = blockIdx.y * 64, r0 = blockIdx.x * 64;
  const int tid = threadIdx.x;
#pragma unroll
  for (int it = 0; it < 2; it++) {
    int f = it * 256 + tid;
    int si = f >> 3, cj = (f & 7) << 3;
    *(short8_t*)(&t[si][cj]) = *(const short8_t*)(v + (size_t)(s0 + si) * 2048 + r0 + cj);
  }
  __syncthreads();
#pragma unroll
  for (int it = 0; it < 2; it++) {
    int f = it * 256 + tid;
    int ri = f >> 3, sj = (f & 7) << 3;
    short8_t o;
#pragma unroll
    for (int jj = 0; jj < 8; jj++) o[jj] = t[sj + jj][ri];
    *(short8_t*)(vT + (size_t)(r0 + ri) * SEQ + s0 + sj) = o;
  }
}

// ============================================================================
// Barrier-free flash attention. Block = 4 waves = the 4 heads sharing one KV
// head; each wave owns a 16-query tile end-to-end. Scores, softmax state, and
// O live in registers; LDS only for the per-wave P transpose (C->A layout).
// PT[key][q] stride 18 u16: b32 writes / u16 reads both <=2-way conflicts.
// ============================================================================
__global__ __launch_bounds__(256) void attn_kernel(const unsigned short* __restrict__ qb,
                                                   const unsigned short* __restrict__ kb,
                                                   const unsigned short* __restrict__ vT,
                                                   unsigned short* __restrict__ attn_out) {
  const int qt = blockIdx.x, kvh = blockIdx.y;
  const int tid = threadIdx.x;
  const int w = tid >> 6, lane = tid & 63;
  const int quad = lane >> 4, l16 = lane & 15;
  const int h = kvh * 4 + w;
  const int q0 = qt * 16;
  const float SCALE = 0.08838834764831845f;  // 128^-0.5

  __shared__ unsigned short PTs[4][128 * 18 + 8];
  unsigned short* pt = &PTs[w][0];

  // Q A-frags straight from global (lane l16 = q row, k = ks*32+quad*8+j)
  bf16x8_t aq[4];
  {
    const unsigned short* qp = qb + (size_t)(q0 + l16) * 4096 + h * 128 + quad * 8;
#pragma unroll
    for (int ks = 0; ks < 4; ks++)
      aq[ks] = __builtin_bit_cast(bf16x8_t, *(const short8_t*)(qp + ks * 32));
  }

  floatx4_t O[8] = {};
  float m_run[4], l_run[4];
#pragma unroll
  for (int r = 0; r < 4; r++) { m_run[r] = -3e38f; l_run[r] = 0.0f; }

  int kbeg = q0 - (WINDOW - 1); if (kbeg < 0) kbeg = 0;
  const int c0 = kbeg & ~127;
  const int nch = (q0 + 16 - c0 + 127) >> 7;

  for (int ci = 0; ci < nch; ci++) {
    const int kb0 = c0 + (ci << 7);
    // ---- QK: 8 key subtiles, 8 independent MFMA chains ----
    floatx4_t S[8];
#pragma unroll
    for (int st = 0; st < 8; st++) {
      floatx4_t acc = {};
      const unsigned short* kp = kb + (size_t)(kb0 + st * 16 + l16) * 2048 + kvh * 128 + quad * 8;
#pragma unroll
      for (int ks = 0; ks < 4; ks++) {
        bf16x8_t bfk = __builtin_bit_cast(bf16x8_t, *(const short8_t*)(kp + ks * 32));
        acc = __builtin_amdgcn_mfma_f32_16x16x32_bf16(aq[ks], bfk, acc, 0, 0, 0);
      }
      S[st] = acc;
    }
    // ---- mask (wave-uniform branch, only edge chunks) ----
    const bool need_mask = (kb0 + 127 > q0) || (kb0 < q0 - 1008);
    if (need_mask) {
#pragma unroll
      for (int st = 0; st < 8; st++) {
        const int key = kb0 + st * 16 + l16;
#pragma unroll
        for (int r = 0; r < 4; r++) {
          const int i = q0 + quad * 4 + r;
          const bool ok = (key <= i) && (i - key < WINDOW);
          S[st][r] = ok ? S[st][r] : -3e38f;
        }
      }
    }
    // ---- in-register online softmax (row = quad*4+r, reduce over quad's 16 lanes) ----
    float mx[4], rs[4], alpha[4];
#pragma unroll
    for (int r = 0; r < 4; r++) {
      float m = S[0][r];
#pragma unroll
      for (int st = 1; st < 8; st++) m = fmaxf(m, S[st][r]);
#pragma unroll
      for (int d = 1; d < 16; d <<= 1) m = fmaxf(m, __shfl_xor(m, d, 16));
      mx[r] = fmaxf(m_run[r], m);
      alpha[r] = __expf(SCALE * (m_run[r] - mx[r]));
      m_run[r] = mx[r];
      rs[r] = 0.0f;
    }
#pragma unroll
    for (int st = 0; st < 8; st++) {
      float p[4];
#pragma unroll
      for (int r = 0; r < 4; r++) {
        const float sv = S[st][r];
        float e = __expf(SCALE * (sv - mx[r]));
        if (need_mask) e = (sv < -1e37f) ? 0.0f : e;
        p[r] = e;
        rs[r] += e;
      }
      // PT[key][q]: lane holds one key (st*16+l16), q cols quad*4..+3
      uint32 d01 = f2bf_bits(p[0]) | (f2bf_bits(p[1]) << 16);
      uint32 d23 = f2bf_bits(p[2]) | (f2bf_bits(p[3]) << 16);
      uint32* dst = (uint32*)(pt + (st * 16 + l16) * 18 + quad * 4);
      dst[0] = d01;
      dst[1] = d23;
    }
#pragma unroll
    for (int r = 0; r < 4; r++) {
#pragma unroll
      for (int d = 1; d < 16; d <<= 1) rs[r] += __shfl_xor(rs[r], d, 16);
      l_run[r] = l_run[r] * alpha[r] + rs[r];
    }
#pragma unroll
    for (int nt = 0; nt < 8; nt++)
#pragma unroll
      for (int r = 0; r < 4; r++) O[nt][r] *= alpha[r];
    // same-wave LDS write->read: DS ops are wave-in-order; just stop compiler reordering
    asm volatile("" ::: "memory");
    // ---- PV: ks outer (one P A-frag live), 8 O chains inner ----
#pragma unroll
    for (int ks = 0; ks < 4; ks++) {
      short8_t as;
#pragma unroll
      for (int j = 0; j < 8; j++)
        as[j] = (short)pt[(ks * 32 + quad * 8 + j) * 18 + l16];
      bf16x8_t af = __builtin_bit_cast(bf16x8_t, as);
#pragma unroll
      for (int nt = 0; nt < 8; nt++) {
        const unsigned short* vp =
            vT + (size_t)(kvh * 128 + nt * 16 + l16) * SEQ + kb0 + ks * 32 + quad * 8;
        bf16x8_t bfv = __builtin_bit_cast(bf16x8_t, *(const short8_t*)(vp));
        O[nt] = __builtin_amdgcn_mfma_f32_16x16x32_bf16(af, bfv, O[nt], 0, 0, 0);
      }
    }
    asm volatile("" ::: "memory");
  }
  // ---- epilogue ----
  float inv_l[4];
#pragma unroll
  for (int r = 0; r < 4; r++) inv_l[r] = 1.0f / l_run[r];
#pragma unroll
  for (int nt = 0; nt < 8; nt++)
#pragma unroll
    for (int r = 0; r < 4; r++) {
      float v = O[nt][r] * inv_l[r];
      attn_out[(size_t)(q0 + quad * 4 + r) * 4096 + h * 128 + nt * 16 + l16] =
          (unsigned short)f2bf_bits(v);
    }
}

extern "C" void kernel_launch(void* const* d_in, const int* in_sizes, int n_in,
                              void* d_out, int out_size, void* d_ws, size_t ws_size,
                              hipStream_t stream) {
  (void)in_sizes; (void)n_in; (void)out_size; (void)ws_size;
  const float* x    = (const float*)d_in[0];
  const float* wq   = (const float*)d_in[1];
  const float* wk   = (const float*)d_in[2];
  const float* wv   = (const float*)d_in[3];
  const float* wo   = (const float*)d_in[4];
  const float* cosp = (const float*)d_in[5];
  const float* sinp = (const float*)d_in[6];
  float* out = (float*)d_out;
  char* ws = (char*)d_ws;

  // Region map (reuse; 92.3 MB total — round-2 evidence: ws_size suffices):
  //   R1 @0       (33.6MB): wqb        -> attnb @0 (16.8MB), vTb @16.8MB (4.2MB)
  //   R2 @33.6MB  (33.6MB): xb | wkvb  -> wob
  //   qb  @67.1MB (16.8MB), kvb @83.9MB (8.4MB)
  unsigned short* wqb   = (unsigned short*)(ws);
  unsigned short* attnb = (unsigned short*)(ws);
  unsigned short* vTb   = (unsigned short*)(ws + 16777216);
  unsigned short* xb    = (unsigned short*)(ws + 33554432);
  unsigned short* wkvb  = (unsigned short*)(ws + 33554432 + 16777216);
  unsigned short* wob   = (unsigned short*)(ws + 33554432);
  unsigned short* qb    = (unsigned short*)(ws + 67108864);
  unsigned short* kvb   = (unsigned short*)(ws + 83886080);

  cvt_kernel<<<4096, 256, 0, stream>>>(x, xb, SEQ * DIM / 8);
  cvt_kernel<<<8192, 256, 0, stream>>>(wq, wqb, NH * HD * DIM / 8);
  cvt_kernel<<<2048, 256, 0, stream>>>(wk, wkvb, NKV * HD * DIM / 8);
  cvt_kernel<<<2048, 256, 0, stream>>>(wv, wkvb + (size_t)NKV * HD * DIM, NKV * HD * DIM / 8);
  gemm_bf16<unsigned short><<<dim3(32, 16), 256, 0, stream>>>(xb, wqb, qb, SEQ, 4096, DIM);
  gemm_bf16<unsigned short><<<dim3(16, 16), 256, 0, stream>>>(xb, wkvb, kvb, SEQ, 2048, DIM);
  cvt_kernel<<<8192, 256, 0, stream>>>(wo, wob, DIM * NH * HD / 8);
  rope_kernel<<<SEQ * NH * 64 / 256, 256, 0, stream>>>(qb, cosp, sinp, NH, 4096);
  rope_kernel<<<SEQ * NKV * 64 / 256, 256, 0, stream>>>(kvb, cosp, sinp, NKV, 2048);
  vtrans_kernel<<<dim3(16, 32), 256, 0, stream>>>(kvb + 1024, vTb);
  attn_kernel<<<dim3(SEQ / 16, NKV), 256, 0, stream>>>(qb, kvb, vTb, attnb);
  gemm_bf16<float><<<dim3(32, 16), 256, 0, stream>>>(attnb, wob, out, SEQ, 4096, DIM);
}

// Round 4
// 531.896 us; speedup vs baseline: 1.4068x; 1.4068x over previous
//
#include <hip/hip_runtime.h>

#define DIM 4096
#define NH 32
#define NKV 8
#define HD 128
#define WINDOW 1024
#define SEQ 2048

typedef unsigned int uint32;
typedef __attribute__((ext_vector_type(8))) short short8_t;
typedef __attribute__((ext_vector_type(8))) __bf16 bf16x8_t;
typedef __attribute__((ext_vector_type(4))) float floatx4_t;

__device__ __forceinline__ uint32 f2bf_bits(float f) {
  uint32 u = __builtin_bit_cast(uint32, f);
  return (u + 0x7fffu + ((u >> 16) & 1u)) >> 16;
}
__device__ __forceinline__ float bf2f(unsigned short b) {
  return __builtin_bit_cast(float, ((uint32)b) << 16);
}

template <class X, class Y> struct same_t { static constexpr bool v = false; };
template <class X> struct same_t<X, X> { static constexpr bool v = true; };

__device__ __forceinline__ void load_lds16(const unsigned short* g, unsigned short* l) {
  __builtin_amdgcn_global_load_lds((__attribute__((address_space(1))) void*)g,
                                   (__attribute__((address_space(3))) void*)l, 16, 0, 0);
}

// ============================================================================
// bf16 GEMM (m97-style): C[M,N] = A[M,K]*B[N,K]^T, global_load_lds width-16
// staging, XOR col8 swizzle, 128x128 tile, BK=64, 4 waves x (4x4) MFMA.
// ============================================================================
template <typename TC>
__global__ __launch_bounds__(256) void gemm_bf16(const unsigned short* __restrict__ A,
                                                 const unsigned short* __restrict__ B,
                                                 TC* __restrict__ C,
                                                 int M, int N, int K) {
  __shared__ unsigned short As[128 * 64];
  __shared__ unsigned short Bs[128 * 64];
  const int tid = threadIdx.x;
  const int lane = tid & 63, w = tid >> 6;
  const int quad = lane >> 4, l16 = lane & 15;
  const int wm = w >> 1, wn = w & 1;
  const size_t m0 = (size_t)blockIdx.y * 128, n0 = (size_t)blockIdx.x * 128;

  const int srow = tid >> 3;
  const int scol = ((tid & 7) ^ (srow & 7)) << 3;
  const unsigned short* Abase = A + (m0 + srow) * (size_t)K + scol;
  const unsigned short* Bbase = B + (n0 + srow) * (size_t)K + scol;
  unsigned short* ldsA = As + (tid >> 6) * 512;
  unsigned short* ldsB = Bs + (tid >> 6) * 512;

  const int sa = l16 & 7;
  const int raA = wm * 64 + l16;
  const int raB = wn * 64 + l16;

  floatx4_t acc[4][4] = {};

  const int nk = K >> 6;
  for (int kt = 0; kt < nk; kt++) {
    const int kbase = kt << 6;
#pragma unroll
    for (int i = 0; i < 4; i++) {
      load_lds16(Abase + kbase + (size_t)(i * 32) * K, ldsA + i * 2048);
      load_lds16(Bbase + kbase + (size_t)(i * 32) * K, ldsB + i * 2048);
    }
    __syncthreads();
#pragma unroll
    for (int ks = 0; ks < 2; ks++) {
      bf16x8_t af[4], bfg[4];
#pragma unroll
      for (int i = 0; i < 4; i++) {
        const int colA = (((ks << 2) | quad) ^ sa) << 3;
        af[i] = __builtin_bit_cast(bf16x8_t,
            *(const short8_t*)(&As[(raA + i * 16) * 64 + colA]));
      }
#pragma unroll
      for (int j = 0; j < 4; j++) {
        const int colB = (((ks << 2) | quad) ^ sa) << 3;
        bfg[j] = __builtin_bit_cast(bf16x8_t,
            *(const short8_t*)(&Bs[(raB + j * 16) * 64 + colB]));
      }
#pragma unroll
      for (int i = 0; i < 4; i++)
#pragma unroll
        for (int j = 0; j < 4; j++)
          acc[i][j] = __builtin_amdgcn_mfma_f32_16x16x32_bf16(af[i], bfg[j], acc[i][j], 0, 0, 0);
    }
    __syncthreads();
  }
#pragma unroll
  for (int i = 0; i < 4; i++)
#pragma unroll
    for (int j = 0; j < 4; j++)
#pragma unroll
      for (int r = 0; r < 4; r++) {
        size_t row = m0 + wm * 64 + i * 16 + quad * 4 + r;
        size_t col = n0 + wn * 64 + j * 16 + l16;
        float v = acc[i][j][r];
        if constexpr (same_t<TC, float>::v)
          C[row * (size_t)N + col] = v;
        else
          C[row * (size_t)N + col] = (unsigned short)f2bf_bits(v);
      }
}

// fp32 -> bf16 convert, 8 elems/thread
__global__ __launch_bounds__(256) void cvt_kernel(const float* __restrict__ in,
                                                  unsigned short* __restrict__ out, int n8) {
  int idx = blockIdx.x * 256 + threadIdx.x;
  if (idx >= n8) return;
  const float4* p = (const float4*)in + (size_t)idx * 2;
  float4 a = p[0], b = p[1];
  uint32 w0 = f2bf_bits(a.x) | (f2bf_bits(a.y) << 16);
  uint32 w1 = f2bf_bits(a.z) | (f2bf_bits(a.w) << 16);
  uint32 w2 = f2bf_bits(b.x) | (f2bf_bits(b.y) << 16);
  uint32 w3 = f2bf_bits(b.z) | (f2bf_bits(b.w) << 16);
  ((uint4*)out)[idx] = make_uint4(w0, w1, w2, w3);
}

// In-place RoPE on bf16 tensor, leading dim ld, H heads of 128.
__global__ __launch_bounds__(256) void rope_kernel(unsigned short* __restrict__ t,
                                                   const float* __restrict__ cosp,
                                                   const float* __restrict__ sinp,
                                                   int H, int ld) {
  const int idx = blockIdx.x * 256 + threadIdx.x;
  const int j = idx & 63;
  const int rem = idx >> 6;
  const int hh = rem % H;
  const int s = rem / H;
  const size_t base = (size_t)s * ld + hh * 128 + (j << 1);
  const float t0 = bf2f(t[base]), t1 = bf2f(t[base + 1]);
  const float c = cosp[s * 64 + j], sn = sinp[s * 64 + j];
  t[base] = (unsigned short)f2bf_bits(t0 * c - t1 * sn);
  t[base + 1] = (unsigned short)f2bf_bits(t0 * sn + t1 * c);
}

// v [s][r] (ld 2048) -> vT [r][s], 64x64 LDS tiles
__global__ __launch_bounds__(256) void vtrans_kernel(const unsigned short* __restrict__ v,
                                                     unsigned short* __restrict__ vT) {
  __shared__ unsigned short t[64][72];
  const int s0 = blockIdx.y * 64, r0 = blockIdx.x * 64;
  const int tid = threadIdx.x;
#pragma unroll
  for (int it = 0; it < 2; it++) {
    int f = it * 256 + tid;
    int si = f >> 3, cj = (f & 7) << 3;
    *(short8_t*)(&t[si][cj]) = *(const short8_t*)(v + (size_t)(s0 + si) * 2048 + r0 + cj);
  }
  __syncthreads();
#pragma unroll
  for (int it = 0; it < 2; it++) {
    int f = it * 256 + tid;
    int ri = f >> 3, sj = (f & 7) << 3;
    short8_t o;
#pragma unroll
    for (int jj = 0; jj < 8; jj++) o[jj] = t[sj + jj][ri];
    *(short8_t*)(vT + (size_t)(r0 + ri) * SEQ + s0 + sj) = o;
  }
}

// ============================================================================
// GEMM-shaped flash attention. Block = 1 head x 64 queries (4 waves), each
// wave owns 16 query rows end-to-end (in-register online softmax). 64-key
// chunks: K (64x128) and V^T (128x64) staged cooperatively into LDS via
// global_load_lds with XOR col8 swizzle (conflict-free b128 frag reads).
// 32 MFMA per wave between one barrier pair. PT (P transpose, per-wave,
// stride 34 u16) bridges C-layout scores -> A-layout for PV.
// ============================================================================
__global__ __launch_bounds__(256, 3) void attn_kernel(const unsigned short* __restrict__ qb,
                                                      const unsigned short* __restrict__ kb,
                                                      const unsigned short* __restrict__ vT,
                                                      unsigned short* __restrict__ attn_out) {
  const int h = blockIdx.x;
  const int qt = 31 - blockIdx.y;  // heavy qtiles dispatched first
  const int kvh = h >> 2;
  const int q0 = qt * 64;
  const int tid = threadIdx.x;
  const int w = tid >> 6, lane = tid & 63;
  const int quad = lane >> 4, l16 = lane & 15;
  const float SCALE = 0.08838834764831845f;  // 128^-0.5

  __shared__ unsigned short Ks[64 * 128];   // [key][d], XOR col8 swizzled
  __shared__ unsigned short VTs[128 * 64];  // [d][key], XOR col8 swizzled
  __shared__ unsigned short PTs[4 * 64 * 34];  // per-wave [key][q] stride 34

  unsigned short* pt = &PTs[w * 2176];

  // --- staging address precompute (K: 4 issues x 16 rows; VT: 4 x 32 rows) ---
  const int krow = tid >> 4;                       // 0..15
  const int kc16 = tid & 15;
  const int kgcol = (kc16 ^ (krow & 7)) << 3;
  const unsigned short* kgbase = kb + (size_t)krow * 2048 + kvh * 128 + kgcol;
  const int vrow = tid >> 3;                       // 0..31
  const int vc8 = tid & 7;
  const int vgcol = (vc8 ^ (vrow & 7)) << 3;
  const unsigned short* vgbase = vT + (size_t)(kvh * 128 + vrow) * 2048 + vgcol;
  unsigned short* ldsK = Ks + w * 512;
  unsigned short* ldsV = VTs + w * 512;

  // --- Q A-frags from global: wave rows q0 + w*16 + l16 ---
  bf16x8_t aq[4];
  {
    const unsigned short* qp = qb + (size_t)(q0 + w * 16 + l16) * 4096 + h * 128 + quad * 8;
#pragma unroll
    for (int ks = 0; ks < 4; ks++)
      aq[ks] = __builtin_bit_cast(bf16x8_t, *(const short8_t*)(qp + ks * 32));
  }

  floatx4_t O[8] = {};
  float m_run[4], l_run[4];
#pragma unroll
  for (int r = 0; r < 4; r++) { m_run[r] = -3e38f; l_run[r] = 0.0f; }

  const int qmin = q0 + w * 16, qmax = qmin + 15;
  int kbeg = q0 - (WINDOW - 1); if (kbeg < 0) kbeg = 0;
  const int c0 = kbeg & ~63;
  const int nch = (q0 + 64 - c0) >> 6;
  const int sa = l16 & 7;

  for (int ci = 0; ci < nch; ci++) {
    const int kb0 = c0 + (ci << 6);
    // ---- cooperative staging: K chunk 16KB + VT chunk 16KB ----
#pragma unroll
    for (int i = 0; i < 4; i++)
      load_lds16(kgbase + (size_t)(kb0 + i * 16) * 2048, ldsK + i * 2048);
#pragma unroll
    for (int i = 0; i < 4; i++)
      load_lds16(vgbase + kb0 + (size_t)(i * 32) * 2048, ldsV + i * 2048);
    __syncthreads();
    // ---- QK: 4 key subtiles x 4 ks ----
    floatx4_t S[4];
#pragma unroll
    for (int j = 0; j < 4; j++) {
      floatx4_t acc = {};
      const int keyrow = j * 16 + l16;
#pragma unroll
      for (int ks = 0; ks < 4; ks++) {
        const int c16 = ((ks << 2) | quad) ^ sa;
        bf16x8_t bfk = __builtin_bit_cast(bf16x8_t,
            *(const short8_t*)(&Ks[keyrow * 128 + c16 * 8]));
        acc = __builtin_amdgcn_mfma_f32_16x16x32_bf16(aq[ks], bfk, acc, 0, 0, 0);
      }
      S[j] = acc;
    }
    // ---- mask (wave-uniform branch; only edge chunks) ----
    const bool need_mask = (kb0 + 63 > qmin) || (qmax - kb0 >= WINDOW);
    if (need_mask) {
#pragma unroll
      for (int j = 0; j < 4; j++) {
        const int key = kb0 + j * 16 + l16;
#pragma unroll
        for (int r = 0; r < 4; r++) {
          const int i = qmin + quad * 4 + r;
          const bool ok = (key <= i) && (i - key < WINDOW);
          S[j][r] = ok ? S[j][r] : -3e38f;
        }
      }
    }
    // ---- in-register online softmax (row = quad*4+r; reduce over 16 lanes) ----
    float mx[4], rs[4], alpha[4];
#pragma unroll
    for (int r = 0; r < 4; r++) {
      float m = S[0][r];
#pragma unroll
      for (int j = 1; j < 4; j++) m = fmaxf(m, S[j][r]);
#pragma unroll
      for (int d = 1; d < 16; d <<= 1) m = fmaxf(m, __shfl_xor(m, d, 16));
      mx[r] = fmaxf(m_run[r], m);
      alpha[r] = __expf(SCALE * (m_run[r] - mx[r]));
      m_run[r] = mx[r];
      rs[r] = 0.0f;
    }
#pragma unroll
    for (int j = 0; j < 4; j++) {
      float p[4];
#pragma unroll
      for (int r = 0; r < 4; r++) {
        const float sv = S[j][r];
        float e = __expf(SCALE * (sv - mx[r]));
        if (need_mask) e = (sv < -1e37f) ? 0.0f : e;
        p[r] = e;
        rs[r] += e;
      }
      uint32* dst = (uint32*)(pt + (j * 16 + l16) * 34 + quad * 4);
      dst[0] = f2bf_bits(p[0]) | (f2bf_bits(p[1]) << 16);
      dst[1] = f2bf_bits(p[2]) | (f2bf_bits(p[3]) << 16);
    }
#pragma unroll
    for (int r = 0; r < 4; r++) {
#pragma unroll
      for (int d = 1; d < 16; d <<= 1) rs[r] += __shfl_xor(rs[r], d, 16);
      l_run[r] = l_run[r] * alpha[r] + rs[r];
    }
#pragma unroll
    for (int nt = 0; nt < 8; nt++)
#pragma unroll
      for (int r = 0; r < 4; r++) O[nt][r] *= alpha[r];
    // same-wave LDS write->read (DS ops wave-in-order); block compiler reordering
    asm volatile("" ::: "memory");
    // ---- PV: k = 64 keys (2 ks), 8 output d-tiles ----
#pragma unroll
    for (int ks = 0; ks < 2; ks++) {
      short8_t as;
#pragma unroll
      for (int jj = 0; jj < 8; jj++)
        as[jj] = (short)pt[(ks * 32 + quad * 8 + jj) * 34 + l16];
      bf16x8_t af = __builtin_bit_cast(bf16x8_t, as);
#pragma unroll
      for (int nt = 0; nt < 8; nt++) {
        const int c8 = (((ks << 2) | quad) ^ sa);
        bf16x8_t bfv = __builtin_bit_cast(bf16x8_t,
            *(const short8_t*)(&VTs[(nt * 16 + l16) * 64 + c8 * 8]));
        O[nt] = __builtin_amdgcn_mfma_f32_16x16x32_bf16(af, bfv, O[nt], 0, 0, 0);
      }
    }
    __syncthreads();  // before next chunk overwrites Ks/VTs
  }
  // ---- epilogue ----
  float inv_l[4];
#pragma unroll
  for (int r = 0; r < 4; r++) inv_l[r] = 1.0f / l_run[r];
#pragma unroll
  for (int nt = 0; nt < 8; nt++)
#pragma unroll
    for (int r = 0; r < 4; r++) {
      float v = O[nt][r] * inv_l[r];
      attn_out[(size_t)(qmin + quad * 4 + r) * 4096 + h * 128 + nt * 16 + l16] =
          (unsigned short)f2bf_bits(v);
    }
}

extern "C" void kernel_launch(void* const* d_in, const int* in_sizes, int n_in,
                              void* d_out, int out_size, void* d_ws, size_t ws_size,
                              hipStream_t stream) {
  (void)in_sizes; (void)n_in; (void)out_size; (void)ws_size;
  const float* x    = (const float*)d_in[0];
  const float* wq   = (const float*)d_in[1];
  const float* wk   = (const float*)d_in[2];
  const float* wv   = (const float*)d_in[3];
  const float* wo   = (const float*)d_in[4];
  const float* cosp = (const float*)d_in[5];
  const float* sinp = (const float*)d_in[6];
  float* out = (float*)d_out;
  char* ws = (char*)d_ws;

  // Region map (reuse; 92.3 MB total):
  //   R1 @0       (33.6MB): wqb        -> attnb @0 (16.8MB), vTb @16.8MB (4.2MB)
  //   R2 @33.6MB  (33.6MB): xb | wkvb  -> wob
  //   qb  @67.1MB (16.8MB), kvb @83.9MB (8.4MB)
  unsigned short* wqb   = (unsigned short*)(ws);
  unsigned short* attnb = (unsigned short*)(ws);
  unsigned short* vTb   = (unsigned short*)(ws + 16777216);
  unsigned short* xb    = (unsigned short*)(ws + 33554432);
  unsigned short* wkvb  = (unsigned short*)(ws + 33554432 + 16777216);
  unsigned short* wob   = (unsigned short*)(ws + 33554432);
  unsigned short* qb    = (unsigned short*)(ws + 67108864);
  unsigned short* kvb   = (unsigned short*)(ws + 83886080);

  cvt_kernel<<<4096, 256, 0, stream>>>(x, xb, SEQ * DIM / 8);
  cvt_kernel<<<8192, 256, 0, stream>>>(wq, wqb, NH * HD * DIM / 8);
  cvt_kernel<<<2048, 256, 0, stream>>>(wk, wkvb, NKV * HD * DIM / 8);
  cvt_kernel<<<2048, 256, 0, stream>>>(wv, wkvb + (size_t)NKV * HD * DIM, NKV * HD * DIM / 8);
  gemm_bf16<unsigned short><<<dim3(32, 16), 256, 0, stream>>>(xb, wqb, qb, SEQ, 4096, DIM);
  gemm_bf16<unsigned short><<<dim3(16, 16), 256, 0, stream>>>(xb, wkvb, kvb, SEQ, 2048, DIM);
  cvt_kernel<<<8192, 256, 0, stream>>>(wo, wob, DIM * NH * HD / 8);
  rope_kernel<<<SEQ * NH * 64 / 256, 256, 0, stream>>>(qb, cosp, sinp, NH, 4096);
  rope_kernel<<<SEQ * NKV * 64 / 256, 256, 0, stream>>>(kvb, cosp, sinp, NKV, 2048);
  vtrans_kernel<<<dim3(16, 32), 256, 0, stream>>>(kvb + 1024, vTb);
  attn_kernel<<<dim3(NH, 32), 256, 0, stream>>>(qb, kvb, vTb, attnb);
  gemm_bf16<float><<<dim3(32, 16), 256, 0, stream>>>(attnb, wob, out, SEQ, 4096, DIM);
}